// Round 13
// baseline (14850.801 us; speedup 1.0000x reference)
//
#include <hip/hip_runtime.h>
#include <hip/hip_cooperative_groups.h>
#include <math.h>

#define B_ 16
#define N_ 2048
#define M_ 2048
#define ITERS_ 100
// coop kernel: 64-row chunks -> 512 blocks (2/CU co-resident, lb(256,2))
#define NCHC_ 32
// fallback kernels: 32-row chunks -> 1024 blocks (R12-proven)
#define NCHF_ 64
// (1/eps)*log2(e), eps = 0.1
#define SCALE_ 14.426950408889634f
// u16 fixed-point C: Chat = c16/65535
#define KQ_ (SCALE_ / 65535.0f)

namespace cg = cooperative_groups;

typedef float f4 __attribute__((ext_vector_type(4)));
typedef unsigned short u16x8 __attribute__((ext_vector_type(8)));

static __device__ __forceinline__ f4 exp2v(f4 x) {
  return f4{exp2f(x.x), exp2f(x.y), exp2f(x.z), exp2f(x.w)};
}
static __device__ __forceinline__ float hsum(f4 x) {
  return (x.x + x.y) + (x.z + x.w);
}
static __device__ __forceinline__ u16x8 pack16(f4 a, f4 b) {
  u16x8 o;
  o[0] = (unsigned short)rintf(a.x * 65535.f);
  o[1] = (unsigned short)rintf(a.y * 65535.f);
  o[2] = (unsigned short)rintf(a.z * 65535.f);
  o[3] = (unsigned short)rintf(a.w * 65535.f);
  o[4] = (unsigned short)rintf(b.x * 65535.f);
  o[5] = (unsigned short)rintf(b.y * 65535.f);
  o[6] = (unsigned short)rintf(b.z * 65535.f);
  o[7] = (unsigned short)rintf(b.w * 65535.f);
  return o;
}

// ---------------- persistent cooperative kernel ----------------
// Log-domain factorized Sinkhorn (R4/R12-proven math), all 100 iterations,
// F-updates, and the final pi in ONE dispatch.
//   g[n] = p'[n]/rowsum_n, rowsum_n = sum_m 2^(lF[m]-SCALE_*C[n,m])
//   psum[s][b][m] = sum_{n in chunk s} g[n]*2^(lF[m]-SCALE_*C[n,m])
//   lF <- lF + log2(q'/colsum(psum))   (t==1: base 0 -> poison-proof)
// Block (b,s): rows [s*64,s*64+64); 4 waves x 16 rows; lane owns cols
// {k*512+8*lane+j : k=0..3, j=0..7} (16B u16x8 loads).
// t=0 & t=99 read exact fp32 C; t=0 persists u16 T (self-rows only).
__global__ __launch_bounds__(256, 2) void sink_coop(
    const float* __restrict__ C, unsigned short* __restrict__ T,
    const float* __restrict__ p, const float* __restrict__ q,
    float* __restrict__ psum, float* __restrict__ lF_arr,
    float* __restrict__ out) {
  cg::grid_group grid = cg::this_grid();
  __shared__ float lds[4][M_];  // 32 KB
  const int tid = threadIdx.x;
  const int lane = tid & 63, w = tid >> 6;
  const int bid = blockIdx.x;
  const int b = bid >> 5, s = bid & (NCHC_ - 1);
  const int gtid = bid * 256 + tid;
  const int row0 = s * 64 + w * 16;
  const float* prow = p + (size_t)b * N_ + row0;

  float gg[16];
  f4 lF[8];

  for (int t = 0; t < ITERS_; ++t) {
    if (t > 0) {
      // distributed F-update: first 8192 threads, f4 granules
      if (gtid < B_ * M_ / 4) {
        const int bb = gtid >> 9, mg = gtid & 511;
        const f4* P = (const f4*)psum;
        f4 S = f4{0.f, 0.f, 0.f, 0.f};
#pragma unroll 8
        for (int s2 = 0; s2 < NCHC_; s2++)
          S += P[(size_t)(s2 * B_ + bb) * (M_ / 4) + mg];
        f4 qq = ((const f4*)q)[gtid] + 1e-8f;
        f4 r = qq / S;
        f4 lr = f4{log2f(r.x), log2f(r.y), log2f(r.z), log2f(r.w)};
        f4 base = (t == 1) ? f4{0.f, 0.f, 0.f, 0.f} : ((const f4*)lF_arr)[gtid];
        ((f4*)lF_arr)[gtid] = base + lr;
      }
      grid.sync();  // lF ready
      const f4* L = (const f4*)(lF_arr + (size_t)b * M_);
#pragma unroll
      for (int k = 0; k < 4; k++) {
        lF[2 * k] = L[k * 128 + 2 * lane];
        lF[2 * k + 1] = L[k * 128 + 2 * lane + 1];
      }
    } else {
#pragma unroll
      for (int k = 0; k < 8; k++) lF[k] = f4{0.f, 0.f, 0.f, 0.f};
    }

    const bool exact = (t == 0) || (t == ITERS_ - 1);
    f4 sr[8];
#pragma unroll
    for (int k = 0; k < 8; k++) sr[k] = f4{0.f, 0.f, 0.f, 0.f};

#pragma unroll 2
    for (int i = 0; i < 16; i++) {
      const size_t roff = ((size_t)b * N_ + row0 + i) * (size_t)M_;
      f4 e[8];
      float rs = 0.f;
      if (!exact) {
        const u16x8* Tr = (const u16x8*)(T + roff);
#pragma unroll
        for (int k = 0; k < 4; k++) {
          u16x8 tt = Tr[k * 64 + lane];
          f4 x0 = lF[2 * k] -
                  KQ_ * f4{(float)tt[0], (float)tt[1], (float)tt[2], (float)tt[3]};
          f4 x1 = lF[2 * k + 1] -
                  KQ_ * f4{(float)tt[4], (float)tt[5], (float)tt[6], (float)tt[7]};
          e[2 * k] = exp2v(x0);
          e[2 * k + 1] = exp2v(x1);
          rs += hsum(e[2 * k]) + hsum(e[2 * k + 1]);
        }
      } else {
        const f4* Cr = (const f4*)(C + roff);
#pragma unroll
        for (int k = 0; k < 4; k++) {
          f4 c0 = __builtin_nontemporal_load(&Cr[k * 128 + 2 * lane]);
          f4 c1 = __builtin_nontemporal_load(&Cr[k * 128 + 2 * lane + 1]);
          if (t == 0)  // persist u16 T (this block re-reads only these rows)
            ((u16x8*)(T + roff))[k * 64 + lane] = pack16(c0, c1);
          e[2 * k] = exp2v(lF[2 * k] - SCALE_ * c0);
          e[2 * k + 1] = exp2v(lF[2 * k + 1] - SCALE_ * c1);
          rs += hsum(e[2 * k]) + hsum(e[2 * k + 1]);
        }
      }
#pragma unroll
      for (int o = 32; o; o >>= 1) rs += __shfl_xor(rs, o, 64);
      float g = (prow[i] + 1e-8f) / rs;
      gg[i] = g;
#pragma unroll
      for (int k = 0; k < 8; k++) sr[k] += e[k] * g;
    }

    // cross-wave column reduce -> psum
#pragma unroll
    for (int k = 0; k < 4; k++) {
      *(f4*)&lds[w][k * 512 + 8 * lane] = sr[2 * k];
      *(f4*)&lds[w][k * 512 + 8 * lane + 4] = sr[2 * k + 1];
    }
    __syncthreads();
    {
      const int base = w * 512 + 8 * lane;
      f4 a0 = *(const f4*)&lds[0][base] + *(const f4*)&lds[1][base] +
              *(const f4*)&lds[2][base] + *(const f4*)&lds[3][base];
      f4 a1 = *(const f4*)&lds[0][base + 4] + *(const f4*)&lds[1][base + 4] +
              *(const f4*)&lds[2][base + 4] + *(const f4*)&lds[3][base + 4];
      float* po = &psum[(size_t)(s * B_ + b) * M_ + base];
      *(f4*)po = a0;
      *(f4*)(po + 4) = a1;
    }
    grid.sync();  // psum ready; also guards LDS reuse
  }

  // final F-update -> lF_100
  if (gtid < B_ * M_ / 4) {
    const int bb = gtid >> 9, mg = gtid & 511;
    const f4* P = (const f4*)psum;
    f4 S = f4{0.f, 0.f, 0.f, 0.f};
#pragma unroll 8
    for (int s2 = 0; s2 < NCHC_; s2++)
      S += P[(size_t)(s2 * B_ + bb) * (M_ / 4) + mg];
    f4 qq = ((const f4*)q)[gtid] + 1e-8f;
    f4 r = qq / S;
    ((f4*)lF_arr)[gtid] +=
        f4{log2f(r.x), log2f(r.y), log2f(r.z), log2f(r.w)};
  }
  grid.sync();

  // fused pi: out = g[n] * 2^(lF[m] - SCALE_*C)  (exact fp32 C)
  {
    const f4* L = (const f4*)(lF_arr + (size_t)b * M_);
#pragma unroll
    for (int k = 0; k < 4; k++) {
      lF[2 * k] = L[k * 128 + 2 * lane];
      lF[2 * k + 1] = L[k * 128 + 2 * lane + 1];
    }
  }
#pragma unroll 2
  for (int i = 0; i < 16; i++) {
    const size_t roff = ((size_t)b * N_ + row0 + i) * (size_t)M_;
    const f4* Cr = (const f4*)(C + roff);
    f4* Or = (f4*)(out + roff);
    const float g = gg[i];
#pragma unroll
    for (int k = 0; k < 4; k++) {
      f4 c0 = __builtin_nontemporal_load(&Cr[k * 128 + 2 * lane]);
      f4 c1 = __builtin_nontemporal_load(&Cr[k * 128 + 2 * lane + 1]);
      f4 r0 = g * exp2v(lF[2 * k] - SCALE_ * c0);
      f4 r1 = g * exp2v(lF[2 * k + 1] - SCALE_ * c1);
      __builtin_nontemporal_store(r0, &Or[k * 128 + 2 * lane]);
      __builtin_nontemporal_store(r1, &Or[k * 128 + 2 * lane + 1]);
    }
  }
}

// ---------------- fallback path (R12-proven structure) ----------------
__global__ __launch_bounds__(256) void init_kernel(float* __restrict__ lF) {
  lF[blockIdx.x * 256 + threadIdx.x] = 0.f;
}

// Block (b,s): rows [s*32,s*32+32); 4 waves x 8 rows; 16B u16x8 loads.
template <int V>
__global__ __launch_bounds__(256, 2) void sink_iter(
    const float* __restrict__ C, unsigned short* __restrict__ T,
    const float* __restrict__ p, const float* __restrict__ lF_arr,
    float* __restrict__ psum, float* __restrict__ g_out) {
  __shared__ float lds[4][M_];  // 32 KB
  const int tid = threadIdx.x;
  const int lane = tid & 63, w = tid >> 6;
  const int bid = blockIdx.x;
  const int b = bid >> 6, s = bid & (NCHF_ - 1);

  f4 lF[8];
  if (V == 0) {
#pragma unroll
    for (int k = 0; k < 8; k++) lF[k] = f4{0.f, 0.f, 0.f, 0.f};
  } else {
    const f4* L = (const f4*)(lF_arr + (size_t)b * M_);
#pragma unroll
    for (int k = 0; k < 4; k++) {
      lF[2 * k] = L[k * 128 + 2 * lane];
      lF[2 * k + 1] = L[k * 128 + 2 * lane + 1];
    }
  }

  f4 sr[8];
#pragma unroll
  for (int k = 0; k < 8; k++) sr[k] = f4{0.f, 0.f, 0.f, 0.f};

  const int row0 = s * 32 + w * 8;
  const float* prow = p + (size_t)b * N_ + row0;

#pragma unroll 2
  for (int i = 0; i < 8; i++) {
    const size_t roff = ((size_t)b * N_ + row0 + i) * (size_t)M_;
    f4 e[8];
    float rs = 0.f;
    if (V == 1) {
      const u16x8* Tr = (const u16x8*)(T + roff);
#pragma unroll
      for (int k = 0; k < 4; k++) {
        u16x8 tt = Tr[k * 64 + lane];
        f4 x0 = lF[2 * k] -
                KQ_ * f4{(float)tt[0], (float)tt[1], (float)tt[2], (float)tt[3]};
        f4 x1 = lF[2 * k + 1] -
                KQ_ * f4{(float)tt[4], (float)tt[5], (float)tt[6], (float)tt[7]};
        e[2 * k] = exp2v(x0);
        e[2 * k + 1] = exp2v(x1);
        rs += hsum(e[2 * k]) + hsum(e[2 * k + 1]);
      }
    } else {
      const f4* Cr = (const f4*)(C + roff);
#pragma unroll
      for (int k = 0; k < 4; k++) {
        f4 c0 = __builtin_nontemporal_load(&Cr[k * 128 + 2 * lane]);
        f4 c1 = __builtin_nontemporal_load(&Cr[k * 128 + 2 * lane + 1]);
        if (V == 0)
          ((u16x8*)(T + roff))[k * 64 + lane] = pack16(c0, c1);
        e[2 * k] = exp2v(lF[2 * k] - SCALE_ * c0);
        e[2 * k + 1] = exp2v(lF[2 * k + 1] - SCALE_ * c1);
        rs += hsum(e[2 * k]) + hsum(e[2 * k + 1]);
      }
    }
#pragma unroll
    for (int o = 32; o; o >>= 1) rs += __shfl_xor(rs, o, 64);
    float g = (prow[i] + 1e-8f) / rs;
    if (V == 2 && lane == 0) g_out[(size_t)b * N_ + row0 + i] = g;
#pragma unroll
    for (int k = 0; k < 8; k++) sr[k] += e[k] * g;
  }

#pragma unroll
  for (int k = 0; k < 4; k++) {
    *(f4*)&lds[w][k * 512 + 8 * lane] = sr[2 * k];
    *(f4*)&lds[w][k * 512 + 8 * lane + 4] = sr[2 * k + 1];
  }
  __syncthreads();
  {
    const int base = w * 512 + 8 * lane;
    f4 a0 = *(const f4*)&lds[0][base] + *(const f4*)&lds[1][base] +
            *(const f4*)&lds[2][base] + *(const f4*)&lds[3][base];
    f4 a1 = *(const f4*)&lds[0][base + 4] + *(const f4*)&lds[1][base + 4] +
            *(const f4*)&lds[2][base + 4] + *(const f4*)&lds[3][base + 4];
    float* po = &psum[(size_t)(s * B_ + b) * M_ + base];
    *(f4*)po = a0;
    *(f4*)(po + 4) = a1;
  }
}

__global__ __launch_bounds__(256) void lfk_kernel(
    const float* __restrict__ psum, const float* __restrict__ q,
    float* __restrict__ lF) {
  int gid = blockIdx.x * 256 + threadIdx.x;  // b*M_ + m
  int b = gid >> 11;
  int m = gid & (M_ - 1);
  float S = 0.f;
#pragma unroll 8
  for (int s = 0; s < NCHF_; s++)
    S += psum[(size_t)(s * B_ + b) * M_ + m];
  lF[gid] += log2f((q[gid] + 1e-8f) / S);
}

__global__ __launch_bounds__(256) void pi_kernel(
    const float* __restrict__ C, const float* __restrict__ g_arr,
    const float* __restrict__ lF_arr, float* __restrict__ out) {
  int bid = blockIdx.x;
  int tid = threadIdx.x;
  int b = bid >> 11;
  float gg = g_arr[bid];
  const f4* Cr = (const f4*)(C + (size_t)bid * M_);
  const f4* Lr = (const f4*)(lF_arr + (size_t)b * M_);
  f4* Or = (f4*)(out + (size_t)bid * M_);
#pragma unroll
  for (int k = 0; k < 2; k++) {
    int i = tid + (k << 8);
    f4 c = __builtin_nontemporal_load(&Cr[i]);
    f4 L = Lr[i];
    f4 r;
    r.x = gg * exp2f(fmaf(-SCALE_, c.x, L.x));
    r.y = gg * exp2f(fmaf(-SCALE_, c.y, L.y));
    r.z = gg * exp2f(fmaf(-SCALE_, c.z, L.z));
    r.w = gg * exp2f(fmaf(-SCALE_, c.w, L.w));
    __builtin_nontemporal_store(r, &Or[i]);
  }
}

extern "C" void kernel_launch(void* const* d_in, const int* in_sizes, int n_in,
                              void* d_out, int out_size, void* d_ws, size_t ws_size,
                              hipStream_t stream) {
  const float* p = (const float*)d_in[0];
  const float* q = (const float*)d_in[1];
  const float* C = (const float*)d_in[2];
  float* out = (float*)d_out;

  const size_t Telems = (size_t)B_ * N_ * M_;     // 67.1M u16 = 134 MB
  const size_t psz = (size_t)NCHF_ * B_ * M_;     // 8 MB (coop uses first 4)
  const size_t gsz = (size_t)B_ * N_;
  const size_t fsz = (size_t)B_ * M_;
  const size_t need_all =
      Telems * sizeof(unsigned short) + (psz + gsz + fsz) * sizeof(float);

  unsigned short* T;
  float *psum, *g_arr, *lF;
  if (ws_size >= need_all) {
    T = (unsigned short*)d_ws;
    psum = (float*)(T + Telems);
    g_arr = psum + psz;
    lF = g_arr + gsz;
  } else {
    // g,lF in ws (256 KB); T in d_out front (134 MB), psum in d_out tail
    // (8 MB). All scratch in d_out is dead before the pi phase rewrites
    // d_out (pi reads only C/lF/registers or C/g/lF) -> safe, deterministic.
    g_arr = (float*)d_ws;
    lF = g_arr + gsz;
    T = (unsigned short*)d_out;
    psum = out + ((size_t)out_size - psz);
  }

  void* args[7];
  args[0] = (void*)&C;
  args[1] = (void*)&T;
  args[2] = (void*)&p;
  args[3] = (void*)&q;
  args[4] = (void*)&psum;
  args[5] = (void*)&lF;
  args[6] = (void*)&out;
  hipError_t rc = hipLaunchCooperativeKernel(
      (const void*)sink_coop, dim3(B_ * NCHC_), dim3(256), args, 0, stream);
  if (rc == hipSuccess) return;

  // fallback: R12-proven multi-launch path (with 16B T loads)
  init_kernel<<<(B_ * M_) / 256, 256, 0, stream>>>(lF);
  for (int t = 0; t < ITERS_; ++t) {
    if (t == 0)
      sink_iter<0><<<B_ * NCHF_, 256, 0, stream>>>(C, T, p, lF, psum, g_arr);
    else if (t == ITERS_ - 1)
      sink_iter<2><<<B_ * NCHF_, 256, 0, stream>>>(C, T, p, lF, psum, g_arr);
    else
      sink_iter<1><<<B_ * NCHF_, 256, 0, stream>>>(C, T, p, lF, psum, g_arr);
    lfk_kernel<<<(B_ * M_) / 256, 256, 0, stream>>>(psum, q, lF);
  }
  pi_kernel<<<B_ * N_, 256, 0, stream>>>(C, g_arr, lF, out);
}

// Round 14
// 3195.736 us; speedup vs baseline: 4.6471x; 4.6471x over previous
//
#include <hip/hip_runtime.h>
#include <math.h>

#define B_ 16
#define N_ 2048
#define M_ 2048
#define ITERS_ 100
#define RCH_ 32
#define NCH_ (N_ / RCH_)            // 64 chunks -> 1024 blocks
// (1/eps)*log2(e), eps = 0.1
#define SCALE_ 14.426950408889634f
// u8 fixed-point C: Chat = c8/255
#define KQ_ (SCALE_ / 255.0f)

typedef float f4 __attribute__((ext_vector_type(4)));
typedef unsigned char u8x8 __attribute__((ext_vector_type(8)));

static __device__ __forceinline__ f4 exp2v(f4 x) {
  return f4{exp2f(x.x), exp2f(x.y), exp2f(x.z), exp2f(x.w)};
}
static __device__ __forceinline__ float hsum(f4 x) {
  return (x.x + x.y) + (x.z + x.w);
}
static __device__ __forceinline__ u8x8 pack8(f4 a, f4 b) {
  u8x8 o;
  o[0] = (unsigned char)rintf(a.x * 255.f);
  o[1] = (unsigned char)rintf(a.y * 255.f);
  o[2] = (unsigned char)rintf(a.z * 255.f);
  o[3] = (unsigned char)rintf(a.w * 255.f);
  o[4] = (unsigned char)rintf(b.x * 255.f);
  o[5] = (unsigned char)rintf(b.y * 255.f);
  o[6] = (unsigned char)rintf(b.z * 255.f);
  o[7] = (unsigned char)rintf(b.w * 255.f);
  return o;
}

// One fused Sinkhorn iteration (log-domain factorized — R4/R12-proven math):
//   g[n] = p'[n] / rowsum_n,  rowsum_n = sum_m 2^(lF[m] - SCALE_*C[n,m])
//   psum[s][b][m] = sum_{n in chunk s} g[n]*2^(lF[m]-SCALE_*C[n,m]) (F-weighted)
// V=0: first iter — exact fp32 C (NT loads), lF=0, persists u8 T (fused conv).
// V=1: hot iters  — u8 T stream (67 MB, L3-resident; v_cvt_f32_ubyte unpack).
// V=2: last iter  — exact fp32 C, writes g_out.
// Quantization note: u8 kernel perturbation is softmax-averaged in the
// potentials (measured at fp32 floor for u16 AND 12-bit); large pi entries
// are pinned by the marginals; direct term killed by exact t=99 + pi.
// Block (b,s): rows [s*32,s*32+32); 4 waves x 8 rows; lane owns cols
// {k*512 + 8*lane + j : k=0..3, j=0..7} (8B u8x8 loads).
template <int V>
__global__ __launch_bounds__(256, 2) void sink_iter(
    const float* __restrict__ C, unsigned char* __restrict__ T,
    const float* __restrict__ p, const float* __restrict__ lF_arr,
    float* __restrict__ psum, float* __restrict__ g_out) {
  __shared__ float lds[4][M_];  // 32 KB
  const int tid = threadIdx.x;
  const int lane = tid & 63, w = tid >> 6;
  const int bid = blockIdx.x;
  const int b = bid >> 6, s = bid & (NCH_ - 1);

  f4 lF[8];
  if (V == 0) {
#pragma unroll
    for (int k = 0; k < 8; k++) lF[k] = f4{0.f, 0.f, 0.f, 0.f};
  } else {
    const f4* L = (const f4*)(lF_arr + (size_t)b * M_);
#pragma unroll
    for (int k = 0; k < 4; k++) {
      lF[2 * k] = L[k * 128 + 2 * lane];
      lF[2 * k + 1] = L[k * 128 + 2 * lane + 1];
    }
  }

  f4 sr[8];
#pragma unroll
  for (int k = 0; k < 8; k++) sr[k] = f4{0.f, 0.f, 0.f, 0.f};

  const int row0 = s * RCH_ + w * 8;
  const float* prow = p + (size_t)b * N_ + row0;

#pragma unroll 2
  for (int i = 0; i < 8; i++) {
    const size_t roff = ((size_t)b * N_ + row0 + i) * (size_t)M_;
    f4 e[8];
    float rs = 0.f;
    if (V == 1) {
      const u8x8* Tr = (const u8x8*)(T + roff);
#pragma unroll
      for (int k = 0; k < 4; k++) {
        u8x8 tt = Tr[k * 64 + lane];
        f4 x0 = lF[2 * k] -
                KQ_ * f4{(float)tt[0], (float)tt[1], (float)tt[2], (float)tt[3]};
        f4 x1 = lF[2 * k + 1] -
                KQ_ * f4{(float)tt[4], (float)tt[5], (float)tt[6], (float)tt[7]};
        e[2 * k] = exp2v(x0);
        e[2 * k + 1] = exp2v(x1);
        rs += hsum(e[2 * k]) + hsum(e[2 * k + 1]);
      }
    } else {
      const f4* Cr = (const f4*)(C + roff);
#pragma unroll
      for (int k = 0; k < 4; k++) {
        f4 c0 = __builtin_nontemporal_load(&Cr[k * 128 + 2 * lane]);
        f4 c1 = __builtin_nontemporal_load(&Cr[k * 128 + 2 * lane + 1]);
        if (V == 0)  // persist u8 T for hot iterations (fused conv)
          ((u8x8*)(T + roff))[k * 64 + lane] = pack8(c0, c1);
        e[2 * k] = exp2v(lF[2 * k] - SCALE_ * c0);
        e[2 * k + 1] = exp2v(lF[2 * k + 1] - SCALE_ * c1);
        rs += hsum(e[2 * k]) + hsum(e[2 * k + 1]);
      }
    }
#pragma unroll
    for (int o = 32; o; o >>= 1) rs += __shfl_xor(rs, o, 64);
    float g = (prow[i] + 1e-8f) / rs;
    if (V == 2 && lane == 0) g_out[(size_t)b * N_ + row0 + i] = g;
#pragma unroll
    for (int k = 0; k < 8; k++) sr[k] += e[k] * g;
  }

  // cross-wave column reduction -> psum (F-weighted colsums)
#pragma unroll
  for (int k = 0; k < 4; k++) {
    *(f4*)&lds[w][k * 512 + 8 * lane] = sr[2 * k];
    *(f4*)&lds[w][k * 512 + 8 * lane + 4] = sr[2 * k + 1];
  }
  __syncthreads();
  {
    const int base = w * 512 + 8 * lane;
    f4 a0 = *(const f4*)&lds[0][base] + *(const f4*)&lds[1][base] +
            *(const f4*)&lds[2][base] + *(const f4*)&lds[3][base];
    f4 a1 = *(const f4*)&lds[0][base + 4] + *(const f4*)&lds[1][base + 4] +
            *(const f4*)&lds[2][base + 4] + *(const f4*)&lds[3][base + 4];
    float* po = &psum[(size_t)(s * B_ + b) * M_ + base];
    *(f4*)po = a0;
    *(f4*)(po + 4) = a1;
  }
}

// lF update (log-domain, multiplicative — psum includes F):
//   FIRST=1 (t==0): lF = log2(q'/S)   (assignment -> poison-proof, no init)
//   else:           lF += log2(q'/S)
template <int FIRST>
__global__ __launch_bounds__(256) void lfk_kernel(
    const float* __restrict__ psum, const float* __restrict__ q,
    float* __restrict__ lF) {
  int gid = blockIdx.x * 256 + threadIdx.x;  // b*M_ + m
  int b = gid >> 11;
  int m = gid & (M_ - 1);
  float S = 0.f;
#pragma unroll 8
  for (int s = 0; s < NCH_; s++)
    S += psum[(size_t)(s * B_ + b) * M_ + m];
  float lr = log2f((q[gid] + 1e-8f) / S);
  if (FIRST) lF[gid] = lr;
  else lF[gid] += lr;
}

// pi = g[n] * 2^(lF[m] - SCALE_*C)  (exact fp32 C)
__global__ __launch_bounds__(256) void pi_kernel(
    const float* __restrict__ C, const float* __restrict__ g_arr,
    const float* __restrict__ lF_arr, float* __restrict__ out) {
  int bid = blockIdx.x;
  int tid = threadIdx.x;
  int b = bid >> 11;
  float gg = g_arr[bid];
  const f4* Cr = (const f4*)(C + (size_t)bid * M_);
  const f4* Lr = (const f4*)(lF_arr + (size_t)b * M_);
  f4* Or = (f4*)(out + (size_t)bid * M_);
#pragma unroll
  for (int k = 0; k < 2; k++) {
    int i = tid + (k << 8);
    f4 c = __builtin_nontemporal_load(&Cr[i]);
    f4 L = Lr[i];
    f4 r;
    r.x = gg * exp2f(fmaf(-SCALE_, c.x, L.x));
    r.y = gg * exp2f(fmaf(-SCALE_, c.y, L.y));
    r.z = gg * exp2f(fmaf(-SCALE_, c.z, L.z));
    r.w = gg * exp2f(fmaf(-SCALE_, c.w, L.w));
    __builtin_nontemporal_store(r, &Or[i]);
  }
}

extern "C" void kernel_launch(void* const* d_in, const int* in_sizes, int n_in,
                              void* d_out, int out_size, void* d_ws, size_t ws_size,
                              hipStream_t stream) {
  const float* p = (const float*)d_in[0];
  const float* q = (const float*)d_in[1];
  const float* C = (const float*)d_in[2];
  float* out = (float*)d_out;

  const size_t Telems = (size_t)B_ * N_ * M_;     // 67.1M u8 = 67 MB
  const size_t psz = (size_t)NCH_ * B_ * M_;      // 2,097,152 floats = 8 MB
  const size_t gsz = (size_t)B_ * N_;
  const size_t fsz = (size_t)B_ * M_;
  const size_t need_all = Telems + (psz + gsz + fsz) * sizeof(float);

  unsigned char* T;
  float *psum, *g_arr, *lF;
  if (ws_size >= need_all) {
    T = (unsigned char*)d_ws;
    psum = (float*)(T + Telems);
    g_arr = psum + psz;
    lF = g_arr + gsz;
  } else {
    // g,lF in ws (256 KB); T in d_out front (67 MB), psum in d_out tail
    // (8 MB). T last read at t=98, psum last read by the final lfk;
    // pi_kernel then rewrites all of d_out reading only C/g/lF -> safe,
    // deterministic (no cross-call state).
    g_arr = (float*)d_ws;
    lF = g_arr + gsz;
    T = (unsigned char*)d_out;
    psum = out + ((size_t)out_size - psz);
  }

  for (int t = 0; t < ITERS_; ++t) {
    if (t == 0)
      sink_iter<0><<<B_ * NCH_, 256, 0, stream>>>(C, T, p, lF, psum, g_arr);
    else if (t == ITERS_ - 1)
      sink_iter<2><<<B_ * NCH_, 256, 0, stream>>>(C, T, p, lF, psum, g_arr);
    else
      sink_iter<1><<<B_ * NCH_, 256, 0, stream>>>(C, T, p, lF, psum, g_arr);
    if (t == 0)
      lfk_kernel<1><<<(B_ * M_) / 256, 256, 0, stream>>>(psum, q, lF);
    else
      lfk_kernel<0><<<(B_ * M_) / 256, 256, 0, stream>>>(psum, q, lF);
  }
  pi_kernel<<<B_ * N_, 256, 0, stream>>>(C, g_arr, lF, out);
}